// Round 1
// baseline (5105.532 us; speedup 1.0000x reference)
//
#include <hip/hip_runtime.h>
#include <hip/hip_bf16.h>

#define B_  2
#define T_  2048
#define D_  1024
#define H_  16
#define HD_ 64

// ---------------- GEMM: C[M,N] = A[M,K] @ B[N,K]^T (fp32, NT) ----------------
#define BM 128
#define BN 64
#define BK 16

__launch_bounds__(256)
__global__ void gemm_nt(const float* __restrict__ A, const float* __restrict__ Bw,
                        float* __restrict__ C, int M, int N, int K) {
  __shared__ float As[BK][BM + 4];   // transposed tile: As[k][m], stride 132 (16B-aligned rows)
  __shared__ float Bs[BK][BN + 4];   // transposed tile: Bs[k][n], stride 68
  const int tid = threadIdx.x;
  const int bm = blockIdx.y * BM;
  const int bn = blockIdx.x * BN;
  const int tm = (tid >> 4) << 3;    // 16 thread-rows x 8 = 128
  const int tn = (tid & 15) << 2;    // 16 thread-cols x 4 = 64
  float acc[8][4];
#pragma unroll
  for (int i = 0; i < 8; i++)
#pragma unroll
    for (int j = 0; j < 4; j++) acc[i][j] = 0.f;

  for (int k0 = 0; k0 < K; k0 += BK) {
    // A tile: 128 rows x 16 k = 512 float4, 2 per thread
#pragma unroll
    for (int i = 0; i < 2; i++) {
      int idx = tid + i * 256;
      int r = idx >> 2, c4 = idx & 3;
      float4 a = *(const float4*)(A + (size_t)(bm + r) * K + k0 + c4 * 4);
      As[c4 * 4 + 0][r] = a.x; As[c4 * 4 + 1][r] = a.y;
      As[c4 * 4 + 2][r] = a.z; As[c4 * 4 + 3][r] = a.w;
    }
    // B tile: 64 rows x 16 k = 256 float4, 1 per thread
    {
      int r = tid >> 2, c4 = tid & 3;
      float4 b = *(const float4*)(Bw + (size_t)(bn + r) * K + k0 + c4 * 4);
      Bs[c4 * 4 + 0][r] = b.x; Bs[c4 * 4 + 1][r] = b.y;
      Bs[c4 * 4 + 2][r] = b.z; Bs[c4 * 4 + 3][r] = b.w;
    }
    __syncthreads();
#pragma unroll
    for (int k = 0; k < BK; k++) {
      float4 a0 = *(const float4*)&As[k][tm];
      float4 a1 = *(const float4*)&As[k][tm + 4];
      float4 b0 = *(const float4*)&Bs[k][tn];
      float am[8] = {a0.x, a0.y, a0.z, a0.w, a1.x, a1.y, a1.z, a1.w};
      float bv[4] = {b0.x, b0.y, b0.z, b0.w};
#pragma unroll
      for (int i = 0; i < 8; i++)
#pragma unroll
        for (int j = 0; j < 4; j++)
          acc[i][j] = fmaf(am[i], bv[j], acc[i][j]);
    }
    __syncthreads();
  }
#pragma unroll
  for (int i = 0; i < 8; i++) {
    float4 v = make_float4(acc[i][0], acc[i][1], acc[i][2], acc[i][3]);
    *(float4*)(C + (size_t)(bm + tm + i) * N + bn + tn) = v;
  }
}

// ---------------- RoPE on Q and K (in place), folds 1/sqrt(HD) into Q -------
__launch_bounds__(256)
__global__ void rope_kernel(float* __restrict__ Q, float* __restrict__ Kp,
                            const float* __restrict__ cosT, const float* __restrict__ sinT) {
  int i = blockIdx.x * 256 + threadIdx.x;   // over B*T*D elements; lane == d (block mult of 64)
  int d = i & (HD_ - 1);
  int t = (i >> 10) & (T_ - 1);             // H*HD = 1024 = 2^10
  float c = cosT[t * HD_ + d];
  float s = sinT[t * HD_ + d];
  float q = Q[i], k = Kp[i];
  float qp = __shfl_xor(q, 32, 64);         // rotate-half partner: lane d ^ 32
  float kp = __shfl_xor(k, 32, 64);
  float sgn = (d < 32) ? -1.f : 1.f;
  Q[i] = fmaf(sgn * qp, s, q * c) * 0.125f; // fold HD^-0.5 = 1/8 into Q
  Kp[i] = fmaf(sgn * kp, s, k * c);
}

// ---------------- Flash-style causal attention ------------------------------
// grid = (T/64, H, B), block = 256 (4 waves x 16 q-rows each)
// Layouts in LDS:
//   q_s[r*64 + d]                              (broadcast reads, no pad needed)
//   k_s[j*64 + 4*(d4 ^ (j&7)) + e]             (f4-swizzled: aligned b128, even banks)
//   v_s[d*64 + 4*(j4 ^ (d&7)) + e]             (transposed + swizzled)
__launch_bounds__(256)
__global__ void attn_kernel(const float* __restrict__ Q, const float* __restrict__ K,
                            const float* __restrict__ V, float* __restrict__ O) {
  __shared__ float q_s[64 * 64];
  __shared__ float k_s[64 * 64];
  __shared__ float v_s[64 * 64];
  __shared__ float p_s[4][64];
  const int tid = threadIdx.x;
  const int lane = tid & 63;
  const int wv = tid >> 6;
  const int qt = blockIdx.x, h = blockIdx.y, b = blockIdx.z;
  const int q0 = qt * 64;
  const size_t headoff = (size_t)h * HD_;
  const float* Qb = Q + (size_t)b * T_ * D_ + headoff;
  const float* Kb = K + (size_t)b * T_ * D_ + headoff;
  const float* Vb = V + (size_t)b * T_ * D_ + headoff;

  // load Q tile: 64 rows x 16 f4 = 1024 f4, 4 per thread
#pragma unroll
  for (int i = 0; i < 4; i++) {
    int idx = tid + i * 256;
    int r = idx >> 4, c4 = idx & 15;
    float4 qv = *(const float4*)(Qb + (size_t)(q0 + r) * D_ + c4 * 4);
    *(float4*)&q_s[r * 64 + c4 * 4] = qv;
  }
  float o_acc[16], m_i[16], l_i[16];
#pragma unroll
  for (int ii = 0; ii < 16; ii++) { o_acc[ii] = 0.f; m_i[ii] = -1e30f; l_i[ii] = 0.f; }
  __syncthreads();

  for (int kt = 0; kt <= qt; kt++) {
    // stage K (swizzled) and V (transposed+swizzled) tiles
#pragma unroll
    for (int i = 0; i < 4; i++) {
      int idx = tid + i * 256;
      int r = idx >> 4, c4 = idx & 15;
      float4 kv = *(const float4*)(Kb + (size_t)(kt * 64 + r) * D_ + c4 * 4);
      *(float4*)&k_s[r * 64 + 4 * (c4 ^ (r & 7))] = kv;
      float4 vv = *(const float4*)(Vb + (size_t)(kt * 64 + r) * D_ + c4 * 4);
      int j4 = r >> 2, jr = r & 3;
      int d0 = c4 * 4;
      v_s[(d0 + 0) * 64 + 4 * (j4 ^ ((d0 + 0) & 7)) + jr] = vv.x;
      v_s[(d0 + 1) * 64 + 4 * (j4 ^ ((d0 + 1) & 7)) + jr] = vv.y;
      v_s[(d0 + 2) * 64 + 4 * (j4 ^ ((d0 + 2) & 7)) + jr] = vv.z;
      v_s[(d0 + 3) * 64 + 4 * (j4 ^ ((d0 + 3) & 7)) + jr] = vv.w;
    }
    __syncthreads();
    const bool diag = (kt == qt);
    const float4* krow = (const float4*)&k_s[lane * 64];
    const float4* vrow = (const float4*)&v_s[lane * 64];
    const int sw = lane & 7;
#pragma unroll
    for (int ii = 0; ii < 16; ii++) {
      int r = wv * 16 + ii;
      // scores: lane j = lane, dot(Q[r,:], K[j,:])
      float s = 0.f;
      const float4* qrow = (const float4*)&q_s[r * 64];
#pragma unroll
      for (int d4 = 0; d4 < 16; d4++) {
        float4 qv = qrow[d4];
        float4 kv = krow[d4 ^ sw];
        s = fmaf(qv.x, kv.x, fmaf(qv.y, kv.y, fmaf(qv.z, kv.z, fmaf(qv.w, kv.w, s))));
      }
      if (diag && lane > r) s = -1e30f;  // causal mask on diagonal tile
      // online softmax (wave-wide reductions over the 64 k-positions)
      float mx = s;
#pragma unroll
      for (int off = 32; off > 0; off >>= 1) mx = fmaxf(mx, __shfl_xor(mx, off, 64));
      float m_new = fmaxf(m_i[ii], mx);
      float alpha = __expf(m_i[ii] - m_new);
      float p = __expf(s - m_new);
      float ps = p;
#pragma unroll
      for (int off = 32; off > 0; off >>= 1) ps += __shfl_xor(ps, off, 64);
      l_i[ii] = l_i[ii] * alpha + ps;
      m_i[ii] = m_new;
      p_s[wv][lane] = p;
      // PV: lane d = lane, acc = sum_j p[j] * V[j,d]
      float acc = 0.f;
      const float4* prow = (const float4*)&p_s[wv][0];
#pragma unroll
      for (int j4 = 0; j4 < 16; j4++) {
        float4 pv = prow[j4];
        float4 vvv = vrow[j4 ^ sw];
        acc = fmaf(pv.x, vvv.x, fmaf(pv.y, vvv.y, fmaf(pv.z, vvv.z, fmaf(pv.w, vvv.w, acc))));
      }
      o_acc[ii] = o_acc[ii] * alpha + acc;
    }
    __syncthreads();
  }
  // epilogue: normalize and write [B,T,H*HD]
#pragma unroll
  for (int ii = 0; ii < 16; ii++) {
    int r = wv * 16 + ii;
    O[((size_t)b * T_ + q0 + r) * D_ + headoff + lane] = o_acc[ii] / l_i[ii];
  }
}

extern "C" void kernel_launch(void* const* d_in, const int* in_sizes, int n_in,
                              void* d_out, int out_size, void* d_ws, size_t ws_size,
                              hipStream_t stream) {
  const float* x    = (const float*)d_in[0];
  const float* wq   = (const float*)d_in[1];
  const float* wk   = (const float*)d_in[2];
  const float* wv   = (const float*)d_in[3];
  const float* wo   = (const float*)d_in[4];
  const float* cosT = (const float*)d_in[5];
  const float* sinT = (const float*)d_in[6];
  // d_in[7] = causal mask — implicit in the attention kernel, unused
  float* out = (float*)d_out;

  const size_t NTOK = (size_t)B_ * T_;   // 4096
  const size_t SZ   = NTOK * D_;         // 4M floats = 16 MB
  float* Qb = (float*)d_ws;
  float* Kb = Qb + SZ;
  float* Vb = Kb + SZ;
  float* Ab = Vb + SZ;                   // attention output, pre-wo

  dim3 ggrid(D_ / BN, NTOK / BM);        // (16, 32) = 512 blocks
  gemm_nt<<<ggrid, 256, 0, stream>>>(x, wq, Qb, (int)NTOK, D_, D_);
  gemm_nt<<<ggrid, 256, 0, stream>>>(x, wk, Kb, (int)NTOK, D_, D_);
  gemm_nt<<<ggrid, 256, 0, stream>>>(x, wv, Vb, (int)NTOK, D_, D_);
  rope_kernel<<<(int)(SZ / 256), 256, 0, stream>>>(Qb, Kb, cosT, sinT);
  attn_kernel<<<dim3(T_ / 64, H_, B_), 256, 0, stream>>>(Qb, Kb, Vb, Ab);
  gemm_nt<<<ggrid, 256, 0, stream>>>(Ab, wo, out, (int)NTOK, D_, D_);
}

// Round 2
// 767.498 us; speedup vs baseline: 6.6522x; 6.6522x over previous
//
#include <hip/hip_runtime.h>
#include <hip/hip_bf16.h>
#include <type_traits>

#define B_  2
#define T_  2048
#define D_  1024
#define H_  16
#define HD_ 64

typedef __attribute__((ext_vector_type(8))) short bf16x8;
typedef __attribute__((ext_vector_type(4))) float f32x4;

__device__ __forceinline__ unsigned short f2b(float x) {
  union { __hip_bfloat16 h; unsigned short u; } c;
  c.h = __float2bfloat16(x);
  return c.u;
}
__device__ __forceinline__ float b2f(unsigned short u) {
  union { unsigned short u; __hip_bfloat16 h; } c;
  c.u = u;
  return __bfloat162float(c.h);
}

// ---------------- GEMM: C[M,N] = A[M,K] @ B[N,K]^T (fp32 compute) -----------
#define BM 128
#define BN 64
#define BK 16

template <typename OutT>
__global__ void __launch_bounds__(256)
gemm_nt(const float* __restrict__ A, const float* __restrict__ Bw,
        OutT* __restrict__ C, int M, int N, int K) {
  __shared__ float As[BK][BM + 4];
  __shared__ float Bs[BK][BN + 4];
  const int tid = threadIdx.x;
  const int bm = blockIdx.y * BM;
  const int bn = blockIdx.x * BN;
  const int tm = (tid >> 4) << 3;
  const int tn = (tid & 15) << 2;
  float acc[8][4];
#pragma unroll
  for (int i = 0; i < 8; i++)
#pragma unroll
    for (int j = 0; j < 4; j++) acc[i][j] = 0.f;

  for (int k0 = 0; k0 < K; k0 += BK) {
#pragma unroll
    for (int i = 0; i < 2; i++) {
      int idx = tid + i * 256;
      int r = idx >> 2, c4 = idx & 3;
      float4 a = *(const float4*)(A + (size_t)(bm + r) * K + k0 + c4 * 4);
      As[c4 * 4 + 0][r] = a.x; As[c4 * 4 + 1][r] = a.y;
      As[c4 * 4 + 2][r] = a.z; As[c4 * 4 + 3][r] = a.w;
    }
    {
      int r = tid >> 2, c4 = tid & 3;
      float4 b = *(const float4*)(Bw + (size_t)(bn + r) * K + k0 + c4 * 4);
      Bs[c4 * 4 + 0][r] = b.x; Bs[c4 * 4 + 1][r] = b.y;
      Bs[c4 * 4 + 2][r] = b.z; Bs[c4 * 4 + 3][r] = b.w;
    }
    __syncthreads();
#pragma unroll
    for (int k = 0; k < BK; k++) {
      float4 a0 = *(const float4*)&As[k][tm];
      float4 a1 = *(const float4*)&As[k][tm + 4];
      float4 b0 = *(const float4*)&Bs[k][tn];
      float am[8] = {a0.x, a0.y, a0.z, a0.w, a1.x, a1.y, a1.z, a1.w};
      float bv[4] = {b0.x, b0.y, b0.z, b0.w};
#pragma unroll
      for (int i = 0; i < 8; i++)
#pragma unroll
        for (int j = 0; j < 4; j++)
          acc[i][j] = fmaf(am[i], bv[j], acc[i][j]);
    }
    __syncthreads();
  }
#pragma unroll
  for (int i = 0; i < 8; i++) {
    if constexpr (std::is_same_v<OutT, float>) {
      float4 v = make_float4(acc[i][0], acc[i][1], acc[i][2], acc[i][3]);
      *(float4*)(C + (size_t)(bm + tm + i) * N + bn + tn) = v;
    } else {
      unsigned short hv[4];
#pragma unroll
      for (int j = 0; j < 4; j++) hv[j] = f2b(acc[i][j]);
      *(uint2*)(C + (size_t)(bm + tm + i) * N + bn + tn) = *(uint2*)hv;
    }
  }
}

// ---------------- RoPE on bf16 Q and K (in place), folds 1/8 into Q ---------
__global__ void __launch_bounds__(256)
rope_kernel(unsigned short* __restrict__ Q, unsigned short* __restrict__ Kp,
            const float* __restrict__ cosT, const float* __restrict__ sinT) {
  int i = blockIdx.x * 256 + threadIdx.x;   // lane == d (block mult of 64)
  int d = i & (HD_ - 1);
  int t = (i >> 10) & (T_ - 1);
  float c = cosT[t * HD_ + d];
  float s = sinT[t * HD_ + d];
  float q = b2f(Q[i]), k = b2f(Kp[i]);
  float qp = __shfl_xor(q, 32, 64);
  float kp = __shfl_xor(k, 32, 64);
  float sgn = (d < 32) ? -1.f : 1.f;
  Q[i] = f2b(fmaf(sgn * qp, s, q * c) * 0.125f);
  Kp[i] = f2b(fmaf(sgn * kp, s, k * c));
}

// ---------------- MFMA flash attention (bf16 in, fp32 out) ------------------
// grid = (T/64, H, B), block = 256 = 4 waves, each wave owns 16 q-rows.
// MFMA 16x16x32 bf16: A[m=lane&15][k=quad*8+j], B[k=quad*8+j][n=lane&15],
// C/D: col=lane&15, row=quad*4+reg.   (verified: learn_hip m89/m91)
__global__ void __launch_bounds__(256)
attn_kernel(const unsigned short* __restrict__ Q, const unsigned short* __restrict__ K,
            const unsigned short* __restrict__ V, float* __restrict__ O) {
  __shared__ __align__(16) unsigned short q_s[64][72];
  __shared__ __align__(16) unsigned short k_s[64][72];
  __shared__ __align__(16) unsigned short vt_s[64][72];   // vt_s[d][j], j-blocks swizzled by d>>3
  __shared__ __align__(16) unsigned short p_s[4][16][72]; // per-wave P staging

  const int tid = threadIdx.x;
  const int lane = tid & 63;
  const int w = tid >> 6;
  const int m16 = lane & 15;
  const int quad = lane >> 4;
  const int qt = blockIdx.x, h = blockIdx.y, b = blockIdx.z;
  const int q0 = qt * 64;
  const unsigned short* Qb = Q + ((size_t)b * T_ + q0) * D_ + h * HD_;
  const unsigned short* Kb = K + (size_t)b * T_ * D_ + h * HD_;
  const unsigned short* Vb = V + (size_t)b * T_ * D_ + h * HD_;

  // stage Q tile: 64 rows x 8 chunks(16B), 2 chunks/thread
#pragma unroll
  for (int i = 0; i < 2; i++) {
    int idx = tid + i * 256;
    int r = idx >> 3, c = idx & 7;
    *(bf16x8*)&q_s[r][c * 8] = *(const bf16x8*)(Qb + (size_t)r * D_ + c * 8);
  }
  __syncthreads();
  // per-wave Q A-frags (2 K-steps of 32)
  bf16x8 a_q0 = *(const bf16x8*)&q_s[w * 16 + m16][quad * 8];
  bf16x8 a_q1 = *(const bf16x8*)&q_s[w * 16 + m16][32 + quad * 8];

  f32x4 o_acc[4];
  float m_i[4], l_i[4];
#pragma unroll
  for (int r = 0; r < 4; r++) {
    o_acc[r] = (f32x4){0.f, 0.f, 0.f, 0.f};
    m_i[r] = -1e30f;
    l_i[r] = 0.f;
  }

  for (int kt = 0; kt <= qt; kt++) {
    const unsigned short* Kt = Kb + (size_t)(kt * 64) * D_;
    const unsigned short* Vt = Vb + (size_t)(kt * 64) * D_;
    // stage K (row-major) and V^T (swizzled transpose)
#pragma unroll
    for (int i = 0; i < 2; i++) {
      int idx = tid + i * 256;
      int r = idx >> 3, c = idx & 7;          // r = j position, c = d-chunk
      *(bf16x8*)&k_s[r][c * 8] = *(const bf16x8*)(Kt + (size_t)r * D_ + c * 8);
      bf16x8 vv = *(const bf16x8*)(Vt + (size_t)r * D_ + c * 8);
      int jb = r >> 3, jl = r & 7;
#pragma unroll
      for (int e = 0; e < 8; e++) {
        int d = c * 8 + e;
        int jc = ((jb ^ (d >> 3)) << 3) | jl;
        vt_s[d][jc] = ((const unsigned short*)&vv)[e];
      }
    }
    __syncthreads();

    // S = Q K^T : 4 N-tiles x 2 K-steps
    f32x4 s_frag[4];
#pragma unroll
    for (int nt = 0; nt < 4; nt++) {
      bf16x8 b0 = *(const bf16x8*)&k_s[nt * 16 + m16][quad * 8];
      bf16x8 b1 = *(const bf16x8*)&k_s[nt * 16 + m16][32 + quad * 8];
      f32x4 acc = (f32x4){0.f, 0.f, 0.f, 0.f};
      acc = __builtin_amdgcn_mfma_f32_16x16x32_bf16(a_q0, b0, acc, 0, 0, 0);
      acc = __builtin_amdgcn_mfma_f32_16x16x32_bf16(a_q1, b1, acc, 0, 0, 0);
      s_frag[nt] = acc;
    }
    // causal mask on diagonal tile
    if (kt == qt) {
#pragma unroll
      for (int nt = 0; nt < 4; nt++)
#pragma unroll
        for (int reg = 0; reg < 4; reg++) {
          int col = nt * 16 + m16;
          int row = w * 16 + quad * 4 + reg;
          if (col > row) s_frag[nt][reg] = -1e30f;
        }
    }
    // online softmax (rows live on 16-lane groups: lanes with same quad)
    float mt[4], lt[4], alpha[4], p[4][4];
#pragma unroll
    for (int reg = 0; reg < 4; reg++)
      mt[reg] = fmaxf(fmaxf(s_frag[0][reg], s_frag[1][reg]),
                      fmaxf(s_frag[2][reg], s_frag[3][reg]));
#pragma unroll
    for (int off = 1; off < 16; off <<= 1)
#pragma unroll
      for (int reg = 0; reg < 4; reg++)
        mt[reg] = fmaxf(mt[reg], __shfl_xor(mt[reg], off, 64));
#pragma unroll
    for (int reg = 0; reg < 4; reg++) {
      float mn = fmaxf(m_i[reg], mt[reg]);
      alpha[reg] = __expf(m_i[reg] - mn);
      m_i[reg] = mn;
      lt[reg] = 0.f;
    }
#pragma unroll
    for (int nt = 0; nt < 4; nt++)
#pragma unroll
      for (int reg = 0; reg < 4; reg++) {
        p[nt][reg] = __expf(s_frag[nt][reg] - m_i[reg]);
        lt[reg] += p[nt][reg];
      }
#pragma unroll
    for (int off = 1; off < 16; off <<= 1)
#pragma unroll
      for (int reg = 0; reg < 4; reg++)
        lt[reg] += __shfl_xor(lt[reg], off, 64);
#pragma unroll
    for (int reg = 0; reg < 4; reg++) {
      l_i[reg] = l_i[reg] * alpha[reg] + lt[reg];
#pragma unroll
      for (int nt = 0; nt < 4; nt++) o_acc[nt][reg] *= alpha[reg];
    }
    // P: C-layout -> LDS -> A-layout (wave-private, no barrier needed)
#pragma unroll
    for (int nt = 0; nt < 4; nt++)
#pragma unroll
      for (int reg = 0; reg < 4; reg++)
        p_s[w][quad * 4 + reg][nt * 16 + m16] = f2b(p[nt][reg]);
    bf16x8 a_p0 = *(const bf16x8*)&p_s[w][m16][quad * 8];
    bf16x8 a_p1 = *(const bf16x8*)&p_s[w][m16][32 + quad * 8];
    // O += P V : B-frags from swizzled V^T
#pragma unroll
    for (int nt = 0; nt < 4; nt++) {
      int rowd = nt * 16 + m16;
      int jb0 = quad ^ (rowd >> 3);
      int jb1 = (4 + quad) ^ (rowd >> 3);
      bf16x8 b0 = *(const bf16x8*)&vt_s[rowd][jb0 * 8];
      bf16x8 b1 = *(const bf16x8*)&vt_s[rowd][jb1 * 8];
      o_acc[nt] = __builtin_amdgcn_mfma_f32_16x16x32_bf16(a_p0, b0, o_acc[nt], 0, 0, 0);
      o_acc[nt] = __builtin_amdgcn_mfma_f32_16x16x32_bf16(a_p1, b1, o_acc[nt], 0, 0, 0);
    }
    __syncthreads();  // protect k_s/vt_s before next staging
  }

  // epilogue: normalize, write fp32 [B,T,D]
  float inv[4];
#pragma unroll
  for (int reg = 0; reg < 4; reg++) inv[reg] = 1.f / l_i[reg];
  float* Ob = O + ((size_t)b * T_ + q0 + w * 16) * D_ + h * HD_;
#pragma unroll
  for (int nt = 0; nt < 4; nt++)
#pragma unroll
    for (int reg = 0; reg < 4; reg++)
      Ob[(size_t)(quad * 4 + reg) * D_ + nt * 16 + m16] = o_acc[nt][reg] * inv[reg];
}

extern "C" void kernel_launch(void* const* d_in, const int* in_sizes, int n_in,
                              void* d_out, int out_size, void* d_ws, size_t ws_size,
                              hipStream_t stream) {
  const float* x    = (const float*)d_in[0];
  const float* wq   = (const float*)d_in[1];
  const float* wk   = (const float*)d_in[2];
  const float* wv   = (const float*)d_in[3];
  const float* wo   = (const float*)d_in[4];
  const float* cosT = (const float*)d_in[5];
  const float* sinT = (const float*)d_in[6];
  float* out = (float*)d_out;

  const size_t NTOK = (size_t)B_ * T_;   // 4096
  const size_t SZ   = NTOK * D_;         // 4M elements
  unsigned short* Qh = (unsigned short*)d_ws;     // 8 MB
  unsigned short* Kh = Qh + SZ;                   // 8 MB
  unsigned short* Vh = Kh + SZ;                   // 8 MB
  float* Ab = (float*)(Vh + SZ);                  // 16 MB

  dim3 ggrid(D_ / BN, NTOK / BM);        // (16, 32)
  gemm_nt<unsigned short><<<ggrid, 256, 0, stream>>>(x, wq, Qh, (int)NTOK, D_, D_);
  gemm_nt<unsigned short><<<ggrid, 256, 0, stream>>>(x, wk, Kh, (int)NTOK, D_, D_);
  gemm_nt<unsigned short><<<ggrid, 256, 0, stream>>>(x, wv, Vh, (int)NTOK, D_, D_);
  rope_kernel<<<(int)(SZ / 256), 256, 0, stream>>>(Qh, Kh, cosT, sinT);
  attn_kernel<<<dim3(T_ / 64, H_, B_), 256, 0, stream>>>(Qh, Kh, Vh, Ab);
  gemm_nt<float><<<ggrid, 256, 0, stream>>>(Ab, wo, out, (int)NTOK, D_, D_);
}

// Round 3
// 337.502 us; speedup vs baseline: 15.1274x; 2.2741x over previous
//
#include <hip/hip_runtime.h>
#include <hip/hip_bf16.h>
#include <type_traits>

#define B_  2
#define T_  2048
#define D_  1024
#define H_  16
#define HD_ 64

typedef __attribute__((ext_vector_type(8))) short bf16x8;
typedef __attribute__((ext_vector_type(4))) float f32x4;

__device__ __forceinline__ unsigned short f2b(float x) {
  union { __hip_bfloat16 h; unsigned short u; } c;
  c.h = __float2bfloat16(x);
  return c.u;
}
__device__ __forceinline__ float b2f(unsigned short u) {
  union { unsigned short u; __hip_bfloat16 h; } c;
  c.u = u;
  return __bfloat162float(c.h);
}

__device__ __forceinline__ void ld_g2l_16(const unsigned short* g, unsigned short* l) {
  auto gp = (const __attribute__((address_space(1))) unsigned int*)g;
  auto lp = (__attribute__((address_space(3))) unsigned int*)l;
  __builtin_amdgcn_global_load_lds(gp, lp, 16, 0, 0);
}

// ---------------- cast fp32 -> bf16: x (4M) and packed weights (4x1M) -------
__global__ void __launch_bounds__(256)
cast_all(const float* __restrict__ x, const float* __restrict__ wq,
         const float* __restrict__ wk, const float* __restrict__ wv,
         const float* __restrict__ wo, unsigned short* __restrict__ xb,
         unsigned short* __restrict__ wp) {
  int blk = blockIdx.x;
  const float* src;
  unsigned short* dst;
  size_t off;
  if (blk < 2048) {
    src = x; dst = xb; off = (size_t)blk * 2048;
  } else {
    int t = (blk - 2048) >> 9;
    int r = (blk - 2048) & 511;
    src = (t == 0) ? wq : (t == 1) ? wk : (t == 2) ? wv : wo;
    dst = wp + (size_t)t * 1048576;
    off = (size_t)r * 2048;
  }
  size_t i = off + threadIdx.x * 8;
  float4 a = *(const float4*)(src + i);
  float4 b = *(const float4*)(src + i + 4);
  unsigned short h[8] = {f2b(a.x), f2b(a.y), f2b(a.z), f2b(a.w),
                         f2b(b.x), f2b(b.y), f2b(b.z), f2b(b.w)};
  *(uint4*)(dst + i) = *(uint4*)h;
}

// ---------------- MFMA NT GEMM core: C[128,128] tile = A @ B^T --------------
// A: [M,K] bf16, Bw: [N,K] bf16, both row-major; K multiple of 32.
// Pointers pre-offset to the tile origin. m97 structure: BK=32,
// global_load_lds(16B), 4 waves as 2x2, each 64x64 = 4x4 MFMA 16x16x32.
template <typename OutT>
__device__ __forceinline__ void gemm_core(const unsigned short* __restrict__ A,
                                          const unsigned short* __restrict__ Bw,
                                          OutT* __restrict__ C, int K, int Ldc) {
  __shared__ unsigned short a_s[128 * 32];   // row-major, NO pad (global_load_lds)
  __shared__ unsigned short b_s[128 * 32];
  const int tid = threadIdx.x;
  const int lane = tid & 63;
  const int w = tid >> 6;
  const int m16 = lane & 15;
  const int quad = lane >> 4;
  const int wm = w >> 1, wn = w & 1;
  const int rl = lane >> 2;            // 0..15 row within 16-row segment
  const int cl = (lane & 3) * 8;       // bf16 col offset (16 B chunks)

  f32x4 acc[4][4];
#pragma unroll
  for (int i = 0; i < 4; i++)
#pragma unroll
    for (int j = 0; j < 4; j++) acc[i][j] = (f32x4){0.f, 0.f, 0.f, 0.f};

  for (int k0 = 0; k0 < K; k0 += 32) {
    // stage A and B tiles: wave w covers rows w*32 .. w*32+31 (2 instrs each)
#pragma unroll
    for (int j = 0; j < 2; j++) {
      int seg = w * 32 + j * 16;
      ld_g2l_16(A + (size_t)(seg + rl) * K + k0 + cl, &a_s[seg * 32]);
      ld_g2l_16(Bw + (size_t)(seg + rl) * K + k0 + cl, &b_s[seg * 32]);
    }
    __syncthreads();
    bf16x8 af[4], bf[4];
#pragma unroll
    for (int mt = 0; mt < 4; mt++)
      af[mt] = *(const bf16x8*)&a_s[(wm * 64 + mt * 16 + m16) * 32 + quad * 8];
#pragma unroll
    for (int nt = 0; nt < 4; nt++)
      bf[nt] = *(const bf16x8*)&b_s[(wn * 64 + nt * 16 + m16) * 32 + quad * 8];
#pragma unroll
    for (int mt = 0; mt < 4; mt++)
#pragma unroll
      for (int nt = 0; nt < 4; nt++)
        acc[mt][nt] = __builtin_amdgcn_mfma_f32_16x16x32_bf16(af[mt], bf[nt], acc[mt][nt], 0, 0, 0);
    __syncthreads();
  }
  // epilogue: C/D layout col=lane&15, row=quad*4+reg
#pragma unroll
  for (int mt = 0; mt < 4; mt++)
#pragma unroll
    for (int nt = 0; nt < 4; nt++)
#pragma unroll
      for (int reg = 0; reg < 4; reg++) {
        OutT* p = C + (size_t)(wm * 64 + mt * 16 + quad * 4 + reg) * Ldc + wn * 64 + nt * 16 + m16;
        if constexpr (std::is_same_v<OutT, float>) *p = acc[mt][nt][reg];
        else *p = f2b(acc[mt][nt][reg]);
      }
}

// fused QKV: Bw = packed [3072,1024] (wq|wk|wv), out = packed QKVh (3 x [4096,1024])
__global__ void __launch_bounds__(256)
gemm_qkv(const unsigned short* __restrict__ xb, const unsigned short* __restrict__ wp,
         unsigned short* __restrict__ qkv) {
  const int nb = blockIdx.x;           // 0..23
  const int bm = blockIdx.y * 128;
  const int mi = nb >> 3;              // which of Q/K/V
  const int bn = (nb & 7) * 128;       // col within the 1024-wide output
  gemm_core<unsigned short>(xb + (size_t)bm * D_,
                            wp + (size_t)(mi * 1024 + bn) * D_,
                            qkv + (size_t)mi * (4096ull * D_) + (size_t)bm * D_ + bn,
                            D_, D_);
}

__global__ void __launch_bounds__(256)
gemm_out(const unsigned short* __restrict__ Ab, const unsigned short* __restrict__ wob,
         float* __restrict__ C) {
  const int bn = blockIdx.x * 128;
  const int bm = blockIdx.y * 128;
  gemm_core<float>(Ab + (size_t)bm * D_, wob + (size_t)bn * D_,
                   C + (size_t)bm * D_ + bn, D_, D_);
}

// ---------------- RoPE on bf16 Q and K (in place), folds 1/8 into Q ---------
__global__ void __launch_bounds__(256)
rope_kernel(unsigned short* __restrict__ Q, unsigned short* __restrict__ Kp,
            const float* __restrict__ cosT, const float* __restrict__ sinT) {
  int i = blockIdx.x * 256 + threadIdx.x;   // lane == d (block mult of 64)
  int d = i & (HD_ - 1);
  int t = (i >> 10) & (T_ - 1);
  float c = cosT[t * HD_ + d];
  float s = sinT[t * HD_ + d];
  float q = b2f(Q[i]), k = b2f(Kp[i]);
  float qp = __shfl_xor(q, 32, 64);
  float kp = __shfl_xor(k, 32, 64);
  float sgn = (d < 32) ? -1.f : 1.f;
  Q[i] = f2b(fmaf(sgn * qp, s, q * c) * 0.125f);
  Kp[i] = f2b(fmaf(sgn * kp, s, k * c));
}

// ---------------- MFMA flash attention (bf16 in, bf16 out) ------------------
// grid = (T/64, H, B), block = 256 = 4 waves, each wave owns 16 q-rows.
__global__ void __launch_bounds__(256)
attn_kernel(const unsigned short* __restrict__ Q, const unsigned short* __restrict__ K,
            const unsigned short* __restrict__ V, unsigned short* __restrict__ O) {
  __shared__ __align__(16) unsigned short q_s[64][72];
  __shared__ __align__(16) unsigned short k_s[64][72];
  __shared__ __align__(16) unsigned short vt_s[64][72];   // vt_s[d][j], swizzled
  __shared__ __align__(16) unsigned short p_s[4][16][72]; // per-wave P staging

  const int tid = threadIdx.x;
  const int lane = tid & 63;
  const int w = tid >> 6;
  const int m16 = lane & 15;
  const int quad = lane >> 4;
  const int qt = blockIdx.x, h = blockIdx.y, b = blockIdx.z;
  const int q0 = qt * 64;
  const unsigned short* Qb = Q + ((size_t)b * T_ + q0) * D_ + h * HD_;
  const unsigned short* Kb = K + (size_t)b * T_ * D_ + h * HD_;
  const unsigned short* Vb = V + (size_t)b * T_ * D_ + h * HD_;

#pragma unroll
  for (int i = 0; i < 2; i++) {
    int idx = tid + i * 256;
    int r = idx >> 3, c = idx & 7;
    *(bf16x8*)&q_s[r][c * 8] = *(const bf16x8*)(Qb + (size_t)r * D_ + c * 8);
  }
  __syncthreads();
  bf16x8 a_q0 = *(const bf16x8*)&q_s[w * 16 + m16][quad * 8];
  bf16x8 a_q1 = *(const bf16x8*)&q_s[w * 16 + m16][32 + quad * 8];

  f32x4 o_acc[4];
  float m_i[4], l_i[4];
#pragma unroll
  for (int r = 0; r < 4; r++) {
    o_acc[r] = (f32x4){0.f, 0.f, 0.f, 0.f};
    m_i[r] = -1e30f;
    l_i[r] = 0.f;
  }

  for (int kt = 0; kt <= qt; kt++) {
    const unsigned short* Kt = Kb + (size_t)(kt * 64) * D_;
    const unsigned short* Vt = Vb + (size_t)(kt * 64) * D_;
#pragma unroll
    for (int i = 0; i < 2; i++) {
      int idx = tid + i * 256;
      int r = idx >> 3, c = idx & 7;
      *(bf16x8*)&k_s[r][c * 8] = *(const bf16x8*)(Kt + (size_t)r * D_ + c * 8);
      bf16x8 vv = *(const bf16x8*)(Vt + (size_t)r * D_ + c * 8);
      int jb = r >> 3, jl = r & 7;
#pragma unroll
      for (int e = 0; e < 8; e++) {
        int d = c * 8 + e;
        int jc = ((jb ^ (d >> 3)) << 3) | jl;
        vt_s[d][jc] = ((const unsigned short*)&vv)[e];
      }
    }
    __syncthreads();

    f32x4 s_frag[4];
#pragma unroll
    for (int nt = 0; nt < 4; nt++) {
      bf16x8 b0 = *(const bf16x8*)&k_s[nt * 16 + m16][quad * 8];
      bf16x8 b1 = *(const bf16x8*)&k_s[nt * 16 + m16][32 + quad * 8];
      f32x4 acc = (f32x4){0.f, 0.f, 0.f, 0.f};
      acc = __builtin_amdgcn_mfma_f32_16x16x32_bf16(a_q0, b0, acc, 0, 0, 0);
      acc = __builtin_amdgcn_mfma_f32_16x16x32_bf16(a_q1, b1, acc, 0, 0, 0);
      s_frag[nt] = acc;
    }
    if (kt == qt) {
#pragma unroll
      for (int nt = 0; nt < 4; nt++)
#pragma unroll
        for (int reg = 0; reg < 4; reg++) {
          int col = nt * 16 + m16;
          int row = w * 16 + quad * 4 + reg;
          if (col > row) s_frag[nt][reg] = -1e30f;
        }
    }
    float mt[4], lt[4], alpha[4], p[4][4];
#pragma unroll
    for (int reg = 0; reg < 4; reg++)
      mt[reg] = fmaxf(fmaxf(s_frag[0][reg], s_frag[1][reg]),
                      fmaxf(s_frag[2][reg], s_frag[3][reg]));
#pragma unroll
    for (int off = 1; off < 16; off <<= 1)
#pragma unroll
      for (int reg = 0; reg < 4; reg++)
        mt[reg] = fmaxf(mt[reg], __shfl_xor(mt[reg], off, 64));
#pragma unroll
    for (int reg = 0; reg < 4; reg++) {
      float mn = fmaxf(m_i[reg], mt[reg]);
      alpha[reg] = __expf(m_i[reg] - mn);
      m_i[reg] = mn;
      lt[reg] = 0.f;
    }
#pragma unroll
    for (int nt = 0; nt < 4; nt++)
#pragma unroll
      for (int reg = 0; reg < 4; reg++) {
        p[nt][reg] = __expf(s_frag[nt][reg] - m_i[reg]);
        lt[reg] += p[nt][reg];
      }
#pragma unroll
    for (int off = 1; off < 16; off <<= 1)
#pragma unroll
      for (int reg = 0; reg < 4; reg++)
        lt[reg] += __shfl_xor(lt[reg], off, 64);
#pragma unroll
    for (int reg = 0; reg < 4; reg++) {
      l_i[reg] = l_i[reg] * alpha[reg] + lt[reg];
#pragma unroll
      for (int nt = 0; nt < 4; nt++) o_acc[nt][reg] *= alpha[reg];
    }
#pragma unroll
    for (int nt = 0; nt < 4; nt++)
#pragma unroll
      for (int reg = 0; reg < 4; reg++)
        p_s[w][quad * 4 + reg][nt * 16 + m16] = f2b(p[nt][reg]);
    bf16x8 a_p0 = *(const bf16x8*)&p_s[w][m16][quad * 8];
    bf16x8 a_p1 = *(const bf16x8*)&p_s[w][m16][32 + quad * 8];
#pragma unroll
    for (int nt = 0; nt < 4; nt++) {
      int rowd = nt * 16 + m16;
      int jb0 = quad ^ (rowd >> 3);
      int jb1 = (4 + quad) ^ (rowd >> 3);
      bf16x8 b0 = *(const bf16x8*)&vt_s[rowd][jb0 * 8];
      bf16x8 b1 = *(const bf16x8*)&vt_s[rowd][jb1 * 8];
      o_acc[nt] = __builtin_amdgcn_mfma_f32_16x16x32_bf16(a_p0, b0, o_acc[nt], 0, 0, 0);
      o_acc[nt] = __builtin_amdgcn_mfma_f32_16x16x32_bf16(a_p1, b1, o_acc[nt], 0, 0, 0);
    }
    __syncthreads();
  }

  float inv[4];
#pragma unroll
  for (int reg = 0; reg < 4; reg++) inv[reg] = 1.f / l_i[reg];
  unsigned short* Ob = O + ((size_t)b * T_ + q0 + w * 16) * D_ + h * HD_;
#pragma unroll
  for (int nt = 0; nt < 4; nt++)
#pragma unroll
    for (int reg = 0; reg < 4; reg++)
      Ob[(size_t)(quad * 4 + reg) * D_ + nt * 16 + m16] = f2b(o_acc[nt][reg] * inv[reg]);
}

extern "C" void kernel_launch(void* const* d_in, const int* in_sizes, int n_in,
                              void* d_out, int out_size, void* d_ws, size_t ws_size,
                              hipStream_t stream) {
  const float* x    = (const float*)d_in[0];
  const float* wq   = (const float*)d_in[1];
  const float* wk   = (const float*)d_in[2];
  const float* wv   = (const float*)d_in[3];
  const float* wo   = (const float*)d_in[4];
  const float* cosT = (const float*)d_in[5];
  const float* sinT = (const float*)d_in[6];
  float* out = (float*)d_out;

  const size_t NTOK = (size_t)B_ * T_;   // 4096
  const size_t SZ   = NTOK * D_;         // 4M elements
  unsigned short* xb   = (unsigned short*)d_ws;   // 8 MB
  unsigned short* Wp   = xb + SZ;                 // 8 MB (wq|wk|wv|wo, each 1M)
  unsigned short* QKVh = Wp + 4 * 1048576;        // 24 MB (Q|K|V)
  unsigned short* Ab   = QKVh + 3 * SZ;           // 8 MB

  cast_all<<<4096, 256, 0, stream>>>(x, wq, wk, wv, wo, xb, Wp);
  gemm_qkv<<<dim3(24, 32), 256, 0, stream>>>(xb, Wp, QKVh);
  rope_kernel<<<(int)(SZ / 256), 256, 0, stream>>>(QKVh, QKVh + SZ, cosT, sinT);
  attn_kernel<<<dim3(T_ / 64, H_, B_), 256, 0, stream>>>(QKVh, QKVh + SZ, QKVh + 2 * SZ, Ab);
  gemm_out<<<dim3(8, 32), 256, 0, stream>>>(Ab, Wp + 3 * 1048576, out);
}

// Round 4
// 220.459 us; speedup vs baseline: 23.1587x; 1.5309x over previous
//
#include <hip/hip_runtime.h>
#include <hip/hip_bf16.h>
#include <type_traits>

#define B_  2
#define T_  2048
#define D_  1024
#define H_  16
#define HD_ 64

typedef __attribute__((ext_vector_type(8))) short bf16x8;
typedef __attribute__((ext_vector_type(4))) float f32x4;

__device__ __forceinline__ unsigned short f2b(float x) {
  union { __hip_bfloat16 h; unsigned short u; } c;
  c.h = __float2bfloat16(x);
  return c.u;
}
__device__ __forceinline__ float b2f(unsigned short u) {
  union { unsigned short u; __hip_bfloat16 h; } c;
  c.u = u;
  return __bfloat162float(c.h);
}

__device__ __forceinline__ void ld_g2l_16(const unsigned short* g, unsigned short* l) {
  auto gp = (const __attribute__((address_space(1))) unsigned int*)g;
  auto lp = (__attribute__((address_space(3))) unsigned int*)l;
  __builtin_amdgcn_global_load_lds(gp, lp, 16, 0, 0);
}

// ---------------- cast fp32 -> bf16: x (4M) and packed weights (4x1M) -------
__global__ void __launch_bounds__(256)
cast_all(const float* __restrict__ x, const float* __restrict__ wq,
         const float* __restrict__ wk, const float* __restrict__ wv,
         const float* __restrict__ wo, unsigned short* __restrict__ xb,
         unsigned short* __restrict__ wp) {
  int blk = blockIdx.x;
  const float* src;
  unsigned short* dst;
  size_t off;
  if (blk < 2048) {
    src = x; dst = xb; off = (size_t)blk * 2048;
  } else {
    int t = (blk - 2048) >> 9;
    int r = (blk - 2048) & 511;
    src = (t == 0) ? wq : (t == 1) ? wk : (t == 2) ? wv : wo;
    dst = wp + (size_t)t * 1048576;
    off = (size_t)r * 2048;
  }
  size_t i = off + threadIdx.x * 8;
  float4 a = *(const float4*)(src + i);
  float4 b = *(const float4*)(src + i + 4);
  unsigned short h[8] = {f2b(a.x), f2b(a.y), f2b(a.z), f2b(a.w),
                         f2b(b.x), f2b(b.y), f2b(b.z), f2b(b.w)};
  *(uint4*)(dst + i) = *(uint4*)h;
}

// ---------------- MFMA NT GEMM core: C[MROWS,128] tile = A @ B^T ------------
// m97 structure: BK=32, global_load_lds(16B), 4 waves as 2x2.
template <typename OutT, int MROWS>   // MROWS = 128 or 64
__device__ __forceinline__ void gemm_core(const unsigned short* __restrict__ A,
                                          const unsigned short* __restrict__ Bw,
                                          OutT* __restrict__ C, int K, int Ldc) {
  constexpr int MT = MROWS / 32;             // m-tiles per wave
  __shared__ unsigned short a_s[MROWS * 32]; // row-major, NO pad (global_load_lds)
  __shared__ unsigned short b_s[128 * 32];
  const int tid = threadIdx.x;
  const int lane = tid & 63;
  const int w = tid >> 6;
  const int m16 = lane & 15;
  const int quad = lane >> 4;
  const int wm = w >> 1, wn = w & 1;
  const int rl = lane >> 2;            // row within 16-row segment
  const int cl = (lane & 3) * 8;       // bf16 col offset (16 B chunks)

  f32x4 acc[MT][4];
#pragma unroll
  for (int i = 0; i < MT; i++)
#pragma unroll
    for (int j = 0; j < 4; j++) acc[i][j] = (f32x4){0.f, 0.f, 0.f, 0.f};

  for (int k0 = 0; k0 < K; k0 += 32) {
#pragma unroll
    for (int t = 0; t < MROWS / 64; t++) {
      int seg = w * 16 + t * 64;
      ld_g2l_16(A + (size_t)(seg + rl) * K + k0 + cl, &a_s[seg * 32]);
    }
#pragma unroll
    for (int j = 0; j < 2; j++) {
      int seg = w * 32 + j * 16;
      ld_g2l_16(Bw + (size_t)(seg + rl) * K + k0 + cl, &b_s[seg * 32]);
    }
    __syncthreads();
    bf16x8 af[MT], bfr[4];
#pragma unroll
    for (int mt = 0; mt < MT; mt++)
      af[mt] = *(const bf16x8*)&a_s[(wm * (MT * 16) + mt * 16 + m16) * 32 + quad * 8];
#pragma unroll
    for (int nt = 0; nt < 4; nt++)
      bfr[nt] = *(const bf16x8*)&b_s[(wn * 64 + nt * 16 + m16) * 32 + quad * 8];
#pragma unroll
    for (int mt = 0; mt < MT; mt++)
#pragma unroll
      for (int nt = 0; nt < 4; nt++)
        acc[mt][nt] = __builtin_amdgcn_mfma_f32_16x16x32_bf16(af[mt], bfr[nt], acc[mt][nt], 0, 0, 0);
    __syncthreads();
  }
#pragma unroll
  for (int mt = 0; mt < MT; mt++)
#pragma unroll
    for (int nt = 0; nt < 4; nt++)
#pragma unroll
      for (int reg = 0; reg < 4; reg++) {
        OutT* p = C + (size_t)(wm * (MT * 16) + mt * 16 + quad * 4 + reg) * Ldc + wn * 64 + nt * 16 + m16;
        if constexpr (std::is_same_v<OutT, float>) *p = acc[mt][nt][reg];
        else *p = f2b(acc[mt][nt][reg]);
      }
}

// fused QKV: Bw = packed [3072,1024] (wq|wk|wv), out = packed QKVh
__global__ void __launch_bounds__(256)
gemm_qkv(const unsigned short* __restrict__ xb, const unsigned short* __restrict__ wp,
         unsigned short* __restrict__ qkv) {
  const int nb = blockIdx.x;           // 0..23
  const int bm = blockIdx.y * 128;
  const int mi = nb >> 3;
  const int bn = (nb & 7) * 128;
  gemm_core<unsigned short, 128>(xb + (size_t)bm * D_,
                                 wp + (size_t)(mi * 1024 + bn) * D_,
                                 qkv + (size_t)mi * (4096ull * D_) + (size_t)bm * D_ + bn,
                                 D_, D_);
}

__global__ void __launch_bounds__(256)
gemm_out(const unsigned short* __restrict__ Ab, const unsigned short* __restrict__ wob,
         float* __restrict__ C) {
  const int bn = blockIdx.x * 128;
  const int bm = blockIdx.y * 64;
  gemm_core<float, 64>(Ab + (size_t)bm * D_, wob + (size_t)bn * D_,
                       C + (size_t)bm * D_ + bn, D_, D_);
}

// ---------------- RoPE on bf16 Q and K (in place), folds 1/8 into Q ---------
__global__ void __launch_bounds__(256)
rope_kernel(unsigned short* __restrict__ Q, unsigned short* __restrict__ Kp,
            const float* __restrict__ cosT, const float* __restrict__ sinT) {
  int i = blockIdx.x * 256 + threadIdx.x;
  int d = i & (HD_ - 1);
  int t = (i >> 10) & (T_ - 1);
  float c = cosT[t * HD_ + d];
  float s = sinT[t * HD_ + d];
  float q = b2f(Q[i]), k = b2f(Kp[i]);
  float qp = __shfl_xor(q, 32, 64);
  float kp = __shfl_xor(k, 32, 64);
  float sgn = (d < 32) ? -1.f : 1.f;
  Q[i] = f2b(fmaf(sgn * qp, s, q * c) * 0.125f);
  Kp[i] = f2b(fmaf(sgn * kp, s, k * c));
}

// ---------------- MFMA flash attention, S-transposed formulation ------------
// 512 threads = 8 waves, each owns 16 q-rows (128-row q-tile per block).
// S^T = K.Q^T  (A=K[m=j][k=d], B=Q[k=d][n=r]); C-layout: col=r, row=j.
// O^T = V^T.P^T (A=V^T[m=d][k=j], B=P^T[k=j][n=r]); per-lane scalar m/l.
__global__ void __launch_bounds__(512, 4)
attn_kernel(const unsigned short* __restrict__ Q, const unsigned short* __restrict__ K,
            const unsigned short* __restrict__ V, unsigned short* __restrict__ O) {
  __shared__ __align__(16) unsigned short qp_s[128][72];  // Q tile, then P^T rows, then O
  __shared__ __align__(16) unsigned short k_s[64][72];
  __shared__ __align__(16) unsigned short vt_s[64][72];   // vt_s[d][j], j-block XOR swizzle

  const int tid = threadIdx.x;
  const int lane = tid & 63;
  const int w = tid >> 6;              // 0..7
  const int m16 = lane & 15;
  const int quad = lane >> 4;

  // causal-balanced block mapping: halves use qb and 15-qb
  int x = blockIdx.x;
  int bh, qb;
  if (x < 256) { bh = x >> 4; qb = x & 15; }
  else         { bh = 16 + ((x - 256) >> 4); qb = 15 - ((x - 256) & 15); }
  const int b = bh >> 4, h = bh & 15;
  const int q0 = qb * 128;

  const unsigned short* Qb = Q + ((size_t)b * T_ + q0) * D_ + h * HD_;
  const unsigned short* Kb = K + (size_t)b * T_ * D_ + h * HD_;
  const unsigned short* Vb = V + (size_t)b * T_ * D_ + h * HD_;

  // stage Q tile: 128 rows x 8 chunks, 2 per thread
#pragma unroll
  for (int i = 0; i < 2; i++) {
    int idx = tid + i * 512;
    int r = idx >> 3, c = idx & 7;
    *(bf16x8*)&qp_s[r][c * 8] = *(const bf16x8*)(Qb + (size_t)r * D_ + c * 8);
  }
  __syncthreads();
  bf16x8 q_frag[2];
  q_frag[0] = *(const bf16x8*)&qp_s[w * 16 + m16][quad * 8];
  q_frag[1] = *(const bf16x8*)&qp_s[w * 16 + m16][32 + quad * 8];
  // (first in-loop barrier orders these reads before any p-writes to qp_s)

  f32x4 o_acc[4];
#pragma unroll
  for (int dt = 0; dt < 4; dt++) o_acc[dt] = (f32x4){0.f, 0.f, 0.f, 0.f};
  float m_i = -1e30f, l_i = 0.f;
  const int rg = q0 + w * 16 + m16;      // this lane's q-row
  const int rmax = q0 + w * 16 + 15;     // wave's max q-row
  const int ktmax = (q0 + 127) >> 6;

  for (int kt = 0; kt <= ktmax; kt++) {
    // stage K tile (row-major) + V tile (swizzled transpose), 1 chunk each/thread
    {
      int r = tid >> 3, c = tid & 7;
      const unsigned short* Kt = Kb + (size_t)(kt * 64 + r) * D_ + c * 8;
      const unsigned short* Vt = Vb + (size_t)(kt * 64 + r) * D_ + c * 8;
      *(bf16x8*)&k_s[r][c * 8] = *(const bf16x8*)Kt;
      bf16x8 vv = *(const bf16x8*)Vt;
      int jb = r >> 3, jl = r & 7;
#pragma unroll
      for (int e = 0; e < 8; e++) {
        int d = c * 8 + e;
        vt_s[d][((jb ^ (d >> 3)) << 3) | jl] = ((const unsigned short*)&vv)[e];
      }
    }
    __syncthreads();

    if (kt * 64 <= rmax) {   // wave has unmasked rows in this tile
      // S^T tiles: 4 jt x 2 k-steps
      f32x4 sf[4];
#pragma unroll
      for (int jt = 0; jt < 4; jt++) {
        bf16x8 a0 = *(const bf16x8*)&k_s[jt * 16 + m16][quad * 8];
        bf16x8 a1 = *(const bf16x8*)&k_s[jt * 16 + m16][32 + quad * 8];
        f32x4 acc = (f32x4){0.f, 0.f, 0.f, 0.f};
        acc = __builtin_amdgcn_mfma_f32_16x16x32_bf16(a0, q_frag[0], acc, 0, 0, 0);
        acc = __builtin_amdgcn_mfma_f32_16x16x32_bf16(a1, q_frag[1], acc, 0, 0, 0);
        sf[jt] = acc;
      }
      // causal mask (only when tile crosses the wave's diagonal)
      if (kt * 64 + 63 > q0 + w * 16) {
#pragma unroll
        for (int jt = 0; jt < 4; jt++)
#pragma unroll
          for (int reg = 0; reg < 4; reg++) {
            int jg = kt * 64 + jt * 16 + quad * 4 + reg;
            if (jg > rg) sf[jt][reg] = -1e30f;
          }
      }
      // online softmax: per-lane over 16 values + 2 cross-quad shfls
      float mx = sf[0][0];
#pragma unroll
      for (int jt = 0; jt < 4; jt++)
#pragma unroll
        for (int reg = 0; reg < 4; reg++) mx = fmaxf(mx, sf[jt][reg]);
      mx = fmaxf(mx, __shfl_xor(mx, 16, 64));
      mx = fmaxf(mx, __shfl_xor(mx, 32, 64));
      float mn = fmaxf(m_i, mx);
      float alpha = __expf(m_i - mn);
      float lt = 0.f;
      float p[4][4];
#pragma unroll
      for (int jt = 0; jt < 4; jt++)
#pragma unroll
        for (int reg = 0; reg < 4; reg++) {
          p[jt][reg] = __expf(sf[jt][reg] - mn);
          lt += p[jt][reg];
        }
      lt += __shfl_xor(lt, 16, 64);
      lt += __shfl_xor(lt, 32, 64);
      l_i = l_i * alpha + lt;
      m_i = mn;
#pragma unroll
      for (int dt = 0; dt < 4; dt++)
#pragma unroll
        for (int reg = 0; reg < 4; reg++) o_acc[dt][reg] *= alpha;
      // P^T rows -> qp_s (wave-private): 4 packed b64 writes
#pragma unroll
      for (int jt = 0; jt < 4; jt++) {
        unsigned short pk[4] = {f2b(p[jt][0]), f2b(p[jt][1]), f2b(p[jt][2]), f2b(p[jt][3])};
        *(uint2*)&qp_s[w * 16 + m16][jt * 16 + quad * 4] = *(uint2*)pk;
      }
      // O^T += V^T P^T
      bf16x8 bp0 = *(const bf16x8*)&qp_s[w * 16 + m16][quad * 8];
      bf16x8 bp1 = *(const bf16x8*)&qp_s[w * 16 + m16][32 + quad * 8];
#pragma unroll
      for (int dt = 0; dt < 4; dt++) {
        int rowd = dt * 16 + m16;
        bf16x8 a0 = *(const bf16x8*)&vt_s[rowd][((quad ^ (rowd >> 3)) << 3)];
        bf16x8 a1 = *(const bf16x8*)&vt_s[rowd][(((4 + quad) ^ (rowd >> 3)) << 3)];
        o_acc[dt] = __builtin_amdgcn_mfma_f32_16x16x32_bf16(a0, bp0, o_acc[dt], 0, 0, 0);
        o_acc[dt] = __builtin_amdgcn_mfma_f32_16x16x32_bf16(a1, bp1, o_acc[dt], 0, 0, 0);
      }
    }
    __syncthreads();
  }

  // epilogue: normalize, transpose via LDS, coalesced b128 stores
  float inv = 1.f / l_i;
#pragma unroll
  for (int dt = 0; dt < 4; dt++) {
    unsigned short ok[4];
#pragma unroll
    for (int reg = 0; reg < 4; reg++) ok[reg] = f2b(o_acc[dt][reg] * inv);
    *(uint2*)&qp_s[w * 16 + m16][dt * 16 + quad * 4] = *(uint2*)ok;
  }
  __syncthreads();
  unsigned short* Ob = O + ((size_t)b * T_ + q0) * D_ + h * HD_;
#pragma unroll
  for (int i = 0; i < 2; i++) {
    int idx = tid + i * 512;
    int r = idx >> 3, c = idx & 7;
    *(bf16x8*)(Ob + (size_t)r * D_ + c * 8) = *(const bf16x8*)&qp_s[r][c * 8];
  }
}

extern "C" void kernel_launch(void* const* d_in, const int* in_sizes, int n_in,
                              void* d_out, int out_size, void* d_ws, size_t ws_size,
                              hipStream_t stream) {
  const float* x    = (const float*)d_in[0];
  const float* wq   = (const float*)d_in[1];
  const float* wk   = (const float*)d_in[2];
  const float* wv   = (const float*)d_in[3];
  const float* wo   = (const float*)d_in[4];
  const float* cosT = (const float*)d_in[5];
  const float* sinT = (const float*)d_in[6];
  float* out = (float*)d_out;

  const size_t NTOK = (size_t)B_ * T_;   // 4096
  const size_t SZ   = NTOK * D_;         // 4M elements
  unsigned short* xb   = (unsigned short*)d_ws;   // 8 MB
  unsigned short* Wp   = xb + SZ;                 // 8 MB (wq|wk|wv|wo)
  unsigned short* QKVh = Wp + 4 * 1048576;        // 24 MB (Q|K|V)
  unsigned short* Ab   = QKVh + 3 * SZ;           // 8 MB

  cast_all<<<4096, 256, 0, stream>>>(x, wq, wk, wv, wo, xb, Wp);
  gemm_qkv<<<dim3(24, 32), 256, 0, stream>>>(xb, Wp, QKVh);
  rope_kernel<<<(int)(SZ / 256), 256, 0, stream>>>(QKVh, QKVh + SZ, cosT, sinT);
  attn_kernel<<<512, 512, 0, stream>>>(QKVh, QKVh + SZ, QKVh + 2 * SZ, Ab);
  gemm_out<<<dim3(8, 64), 256, 0, stream>>>(Ab, Wp + 3 * 1048576, out);
}

// Round 5
// 208.289 us; speedup vs baseline: 24.5117x; 1.0584x over previous
//
#include <hip/hip_runtime.h>
#include <hip/hip_bf16.h>
#include <type_traits>

#define B_  2
#define T_  2048
#define D_  1024
#define H_  16
#define HD_ 64

typedef __attribute__((ext_vector_type(8))) short bf16x8;
typedef __attribute__((ext_vector_type(4))) float f32x4;

__device__ __forceinline__ unsigned short f2b(float x) {
  union { __hip_bfloat16 h; unsigned short u; } c;
  c.h = __float2bfloat16(x);
  return c.u;
}
__device__ __forceinline__ float b2f(unsigned short u) {
  union { unsigned short u; __hip_bfloat16 h; } c;
  c.u = u;
  return __bfloat162float(c.h);
}

__device__ __forceinline__ void ld_g2l_16(const unsigned short* g, unsigned short* l) {
  auto gp = (const __attribute__((address_space(1))) unsigned int*)g;
  auto lp = (__attribute__((address_space(3))) unsigned int*)l;
  __builtin_amdgcn_global_load_lds(gp, lp, 16, 0, 0);
}

// ---------------- cast fp32 -> bf16: x (4M) and packed weights (4x1M) -------
__global__ void __launch_bounds__(256)
cast_all(const float* __restrict__ x, const float* __restrict__ wq,
         const float* __restrict__ wk, const float* __restrict__ wv,
         const float* __restrict__ wo, unsigned short* __restrict__ xb,
         unsigned short* __restrict__ wp) {
  int blk = blockIdx.x;
  const float* src;
  unsigned short* dst;
  size_t off;
  if (blk < 2048) {
    src = x; dst = xb; off = (size_t)blk * 2048;
  } else {
    int t = (blk - 2048) >> 9;
    int r = (blk - 2048) & 511;
    src = (t == 0) ? wq : (t == 1) ? wk : (t == 2) ? wv : wo;
    dst = wp + (size_t)t * 1048576;
    off = (size_t)r * 2048;
  }
  size_t i = off + threadIdx.x * 8;
  float4 a = *(const float4*)(src + i);
  float4 b = *(const float4*)(src + i + 4);
  unsigned short h[8] = {f2b(a.x), f2b(a.y), f2b(a.z), f2b(a.w),
                         f2b(b.x), f2b(b.y), f2b(b.z), f2b(b.w)};
  *(uint4*)(dst + i) = *(uint4*)h;
}

// ---------------- MFMA NT GEMM core, async double-buffered ------------------
// C[MROWS,128] = A @ B^T. BK=32, global_load_lds(16B), 4 waves as 2x2.
// rope_mode: 0=none, 1=K (rope), 2=Q (rope + 1/8 scale). tok0 = token base.
template <typename OutT, int MROWS>
__device__ __forceinline__ void gemm_core(const unsigned short* __restrict__ A,
                                          const unsigned short* __restrict__ Bw,
                                          OutT* __restrict__ C, int K, int Ldc,
                                          int rope_mode, const float* __restrict__ cosT,
                                          const float* __restrict__ sinT, int tok0) {
  constexpr int MT = MROWS / 32;
  __shared__ unsigned short a_s[2][MROWS * 32];  // no pad (global_load_lds)
  __shared__ unsigned short b_s[2][128 * 32];
  const int tid = threadIdx.x;
  const int lane = tid & 63;
  const int w = tid >> 6;
  const int m16 = lane & 15;
  const int quad = lane >> 4;
  const int wm = w >> 1, wn = w & 1;
  const int rl = lane >> 2;            // row within 16-row segment
  const int cl = (lane & 3) * 8;       // bf16 col offset (16 B chunks)

  f32x4 acc[MT][4];
#pragma unroll
  for (int i = 0; i < MT; i++)
#pragma unroll
    for (int j = 0; j < 4; j++) acc[i][j] = (f32x4){0.f, 0.f, 0.f, 0.f};

  auto stage = [&](int it, int bs) {
    int k0 = it * 32;
#pragma unroll
    for (int t = 0; t < MROWS / 64; t++) {
      int seg = w * 16 + t * 64;
      ld_g2l_16(A + (size_t)(seg + rl) * K + k0 + cl, &a_s[bs][seg * 32]);
    }
#pragma unroll
    for (int j2 = 0; j2 < 2; j2++) {
      int seg = w * 32 + j2 * 16;
      ld_g2l_16(Bw + (size_t)(seg + rl) * K + k0 + cl, &b_s[bs][seg * 32]);
    }
  };

  const int nit = K / 32;
  stage(0, 0);
  __syncthreads();
  for (int it = 0; it < nit; it++) {
    int cur = it & 1;
    if (it + 1 < nit) stage(it + 1, cur ^ 1);   // flies under compute
    bf16x8 af[MT], bfr[4];
#pragma unroll
    for (int mt = 0; mt < MT; mt++)
      af[mt] = *(const bf16x8*)&a_s[cur][(wm * (MT * 16) + mt * 16 + m16) * 32 + quad * 8];
#pragma unroll
    for (int nt = 0; nt < 4; nt++)
      bfr[nt] = *(const bf16x8*)&b_s[cur][(wn * 64 + nt * 16 + m16) * 32 + quad * 8];
#pragma unroll
    for (int mt = 0; mt < MT; mt++)
#pragma unroll
      for (int nt = 0; nt < 4; nt++)
        acc[mt][nt] = __builtin_amdgcn_mfma_f32_16x16x32_bf16(af[mt], bfr[nt], acc[mt][nt], 0, 0, 0);
    __syncthreads();
  }

  // fused RoPE epilogue: partner of col d is d^32 -> frag nt^2, same lane.
  if (rope_mode) {
    float scale = (rope_mode == 2) ? 0.125f : 1.f;
#pragma unroll
    for (int mt = 0; mt < MT; mt++)
#pragma unroll
      for (int reg = 0; reg < 4; reg++) {
        int t = (tok0 + wm * (MT * 16) + mt * 16 + quad * 4 + reg) & (T_ - 1);
#pragma unroll
        for (int nt = 0; nt < 2; nt++) {
          int d = nt * 16 + m16;                 // < 32
          float co = cosT[t * HD_ + d] * scale;
          float si = sinT[t * HD_ + d] * scale;  // sin/cos same at d and d+32
          float lo = acc[mt][nt][reg], hi = acc[mt][nt + 2][reg];
          acc[mt][nt][reg]     = lo * co - hi * si;
          acc[mt][nt + 2][reg] = hi * co + lo * si;
        }
      }
  }
#pragma unroll
  for (int mt = 0; mt < MT; mt++)
#pragma unroll
    for (int nt = 0; nt < 4; nt++)
#pragma unroll
      for (int reg = 0; reg < 4; reg++) {
        OutT* p = C + (size_t)(wm * (MT * 16) + mt * 16 + quad * 4 + reg) * Ldc + wn * 64 + nt * 16 + m16;
        if constexpr (std::is_same_v<OutT, float>) *p = acc[mt][nt][reg];
        else *p = f2b(acc[mt][nt][reg]);
      }
}

// fused QKV + RoPE: Bw = packed [3072,1024] (wq|wk|wv)
__global__ void __launch_bounds__(256)
gemm_qkv(const unsigned short* __restrict__ xb, const unsigned short* __restrict__ wp,
         unsigned short* __restrict__ qkv, const float* __restrict__ cosT,
         const float* __restrict__ sinT) {
  const int nb = blockIdx.x;           // 0..23
  const int bm = blockIdx.y * 128;
  const int mi = nb >> 3;
  const int bn = (nb & 7) * 128;
  const int rope_mode = (mi == 0) ? 2 : (mi == 1) ? 1 : 0;
  gemm_core<unsigned short, 128>(xb + (size_t)bm * D_,
                                 wp + (size_t)(mi * 1024 + bn) * D_,
                                 qkv + (size_t)mi * (4096ull * D_) + (size_t)bm * D_ + bn,
                                 D_, D_, rope_mode, cosT, sinT, bm);
}

__global__ void __launch_bounds__(256)
gemm_out(const unsigned short* __restrict__ Ab, const unsigned short* __restrict__ wob,
         float* __restrict__ C) {
  const int bn = blockIdx.x * 128;
  const int bm = blockIdx.y * 64;
  gemm_core<float, 64>(Ab + (size_t)bm * D_, wob + (size_t)bn * D_,
                       C + (size_t)bm * D_ + bn, D_, D_, 0, nullptr, nullptr, 0);
}

// ---------------- V -> V^T  (VT[b][h][d][t]) --------------------------------
__global__ void __launch_bounds__(256)
vtrans(const unsigned short* __restrict__ V, unsigned short* __restrict__ VT) {
  __shared__ unsigned short tile[64][72];
  const int tid = threadIdx.x;
  const int tb = blockIdx.x, h = blockIdx.y, b = blockIdx.z;
  const unsigned short* Vb = V + ((size_t)b * T_ + tb * 64) * D_ + h * HD_;
  int r = tid >> 2;
  int c = (tid & 3) * 16;
  bf16x8 v0 = *(const bf16x8*)(Vb + (size_t)r * D_ + c);
  bf16x8 v1 = *(const bf16x8*)(Vb + (size_t)r * D_ + c + 8);
#pragma unroll
  for (int e = 0; e < 8; e++) tile[c + e][r] = ((unsigned short*)&v0)[e];
#pragma unroll
  for (int e = 0; e < 8; e++) tile[c + 8 + e][r] = ((unsigned short*)&v1)[e];
  __syncthreads();
  unsigned short* VTb = VT + ((size_t)b * H_ + h) * HD_ * T_ + tb * 64;
  *(bf16x8*)(VTb + (size_t)r * T_ + c)     = *(const bf16x8*)&tile[r][c];
  *(bf16x8*)(VTb + (size_t)r * T_ + c + 8) = *(const bf16x8*)&tile[r][c + 8];
}

// ---------------- MFMA flash attention, S^T form, async dbuf K/V ------------
// 512 threads = 8 waves x 16 q-rows (128-row q-tile). K and V^T tiles staged
// by global_load_lds with XOR-swizzled source chunks (phys chunk = lc ^ (r&7)).
__global__ void __launch_bounds__(512, 4)
attn_kernel(const unsigned short* __restrict__ Q, const unsigned short* __restrict__ K,
            const unsigned short* __restrict__ VT, unsigned short* __restrict__ O) {
  __shared__ __align__(16) unsigned short qp_s[128][72];   // Q tile / P^T / O staging
  __shared__ __align__(16) unsigned short k_s[2][64 * 64]; // row-major 64x64, swizzled
  __shared__ __align__(16) unsigned short vt_s[2][64 * 64];

  const int tid = threadIdx.x;
  const int lane = tid & 63;
  const int w = tid >> 6;              // 0..7
  const int m16 = lane & 15;
  const int quad = lane >> 4;
  const int swz = m16 & 7;
  const int pc0 = quad ^ swz;          // physical chunk for k-step 0
  const int pc1 = pc0 ^ 4;             // k-step 1

  // causal-balanced block mapping
  int x = blockIdx.x;
  int bh, qb;
  if (x < 256) { bh = x >> 4; qb = x & 15; }
  else         { bh = 16 + ((x - 256) >> 4); qb = 15 - ((x - 256) & 15); }
  const int b = bh >> 4, h = bh & 15;
  const int q0 = qb * 128;

  const unsigned short* Qb = Q + ((size_t)b * T_ + q0) * D_ + h * HD_;
  const unsigned short* Kb = K + (size_t)b * T_ * D_ + h * HD_;
  const unsigned short* VTb = VT + ((size_t)b * H_ + h) * HD_ * T_;

  // stage Q tile (manual, padded LDS)
#pragma unroll
  for (int i = 0; i < 2; i++) {
    int idx = tid + i * 512;
    int r = idx >> 3, c = idx & 7;
    *(bf16x8*)&qp_s[r][c * 8] = *(const bf16x8*)(Qb + (size_t)r * D_ + c * 8);
  }

  // async stage of K/VT tile kt: wave w covers rows w*8..w*8+7
  auto stage_kv = [&](int kt, int bs) {
    int r_sub = lane >> 3, c = lane & 7;
    int cs = (c ^ r_sub) * 8;                 // XOR-swizzled source chunk
    int gr = w * 8 + r_sub;
    ld_g2l_16(Kb + (size_t)(kt * 64 + gr) * D_ + cs, &k_s[bs][w * 8 * 64]);
    ld_g2l_16(VTb + (size_t)gr * T_ + kt * 64 + cs, &vt_s[bs][w * 8 * 64]);
  };

  f32x4 o_acc[4];
#pragma unroll
  for (int dt = 0; dt < 4; dt++) o_acc[dt] = (f32x4){0.f, 0.f, 0.f, 0.f};
  float m_i = -1e30f, l_i = 0.f;
  const int rg = q0 + w * 16 + m16;
  const int rmax = q0 + w * 16 + 15;
  const int ktmax = (q0 + 127) >> 6;

  stage_kv(0, 0);
  __syncthreads();   // publishes Q tile + first K/V tile
  bf16x8 q_frag[2];
  q_frag[0] = *(const bf16x8*)&qp_s[w * 16 + m16][quad * 8];
  q_frag[1] = *(const bf16x8*)&qp_s[w * 16 + m16][32 + quad * 8];

  for (int kt = 0; kt <= ktmax; kt++) {
    int cur = kt & 1;
    if (kt < ktmax) stage_kv(kt + 1, cur ^ 1);   // DMA flies under compute

    if (kt * 64 <= rmax) {
      const unsigned short* kc = &k_s[cur][0];
      const unsigned short* vc = &vt_s[cur][0];
      // S^T = K Q^T
      f32x4 sf[4];
#pragma unroll
      for (int jt = 0; jt < 4; jt++) {
        bf16x8 a0 = *(const bf16x8*)&kc[(jt * 16 + m16) * 64 + pc0 * 8];
        bf16x8 a1 = *(const bf16x8*)&kc[(jt * 16 + m16) * 64 + pc1 * 8];
        f32x4 acc = (f32x4){0.f, 0.f, 0.f, 0.f};
        acc = __builtin_amdgcn_mfma_f32_16x16x32_bf16(a0, q_frag[0], acc, 0, 0, 0);
        acc = __builtin_amdgcn_mfma_f32_16x16x32_bf16(a1, q_frag[1], acc, 0, 0, 0);
        sf[jt] = acc;
      }
      if (kt * 64 + 63 > q0 + w * 16) {   // causal mask
#pragma unroll
        for (int jt = 0; jt < 4; jt++)
#pragma unroll
          for (int reg = 0; reg < 4; reg++) {
            int jg = kt * 64 + jt * 16 + quad * 4 + reg;
            if (jg > rg) sf[jt][reg] = -1e30f;
          }
      }
      // online softmax (per-lane row, 2 cross-quad shfls)
      float mx = sf[0][0];
#pragma unroll
      for (int jt = 0; jt < 4; jt++)
#pragma unroll
        for (int reg = 0; reg < 4; reg++) mx = fmaxf(mx, sf[jt][reg]);
      mx = fmaxf(mx, __shfl_xor(mx, 16, 64));
      mx = fmaxf(mx, __shfl_xor(mx, 32, 64));
      float mn = fmaxf(m_i, mx);
      float alpha = __expf(m_i - mn);
      float lt = 0.f;
      float p[4][4];
#pragma unroll
      for (int jt = 0; jt < 4; jt++)
#pragma unroll
        for (int reg = 0; reg < 4; reg++) {
          p[jt][reg] = __expf(sf[jt][reg] - mn);
          lt += p[jt][reg];
        }
      lt += __shfl_xor(lt, 16, 64);
      lt += __shfl_xor(lt, 32, 64);
      l_i = l_i * alpha + lt;
      m_i = mn;
#pragma unroll
      for (int dt = 0; dt < 4; dt++)
#pragma unroll
        for (int reg = 0; reg < 4; reg++) o_acc[dt][reg] *= alpha;
      // P^T rows -> qp_s (wave-private)
#pragma unroll
      for (int jt = 0; jt < 4; jt++) {
        unsigned short pk[4] = {f2b(p[jt][0]), f2b(p[jt][1]), f2b(p[jt][2]), f2b(p[jt][3])};
        *(uint2*)&qp_s[w * 16 + m16][jt * 16 + quad * 4] = *(uint2*)pk;
      }
      bf16x8 bp0 = *(const bf16x8*)&qp_s[w * 16 + m16][quad * 8];
      bf16x8 bp1 = *(const bf16x8*)&qp_s[w * 16 + m16][32 + quad * 8];
      // O^T += V^T P^T
#pragma unroll
      for (int dt = 0; dt < 4; dt++) {
        int rowd = dt * 16 + m16;
        bf16x8 a0 = *(const bf16x8*)&vc[rowd * 64 + pc0 * 8];
        bf16x8 a1 = *(const bf16x8*)&vc[rowd * 64 + pc1 * 8];
        o_acc[dt] = __builtin_amdgcn_mfma_f32_16x16x32_bf16(a0, bp0, o_acc[dt], 0, 0, 0);
        o_acc[dt] = __builtin_amdgcn_mfma_f32_16x16x32_bf16(a1, bp1, o_acc[dt], 0, 0, 0);
      }
    }
    __syncthreads();   // publishes next tile, protects buffer reuse
  }

  // epilogue: normalize, transpose via LDS, coalesced stores
  float inv = 1.f / l_i;
#pragma unroll
  for (int dt = 0; dt < 4; dt++) {
    unsigned short ok[4];
#pragma unroll
    for (int reg = 0; reg < 4; reg++) ok[reg] = f2b(o_acc[dt][reg] * inv);
    *(uint2*)&qp_s[w * 16 + m16][dt * 16 + quad * 4] = *(uint2*)ok;
  }
  __syncthreads();
  unsigned short* Ob = O + ((size_t)b * T_ + q0) * D_ + h * HD_;
#pragma unroll
  for (int i = 0; i < 2; i++) {
    int idx = tid + i * 512;
    int r = idx >> 3, c = idx & 7;
    *(bf16x8*)(Ob + (size_t)r * D_ + c * 8) = *(const bf16x8*)&qp_s[r][c * 8];
  }
}

extern "C" void kernel_launch(void* const* d_in, const int* in_sizes, int n_in,
                              void* d_out, int out_size, void* d_ws, size_t ws_size,
                              hipStream_t stream) {
  const float* x    = (const float*)d_in[0];
  const float* wq   = (const float*)d_in[1];
  const float* wk   = (const float*)d_in[2];
  const float* wv   = (const float*)d_in[3];
  const float* wo   = (const float*)d_in[4];
  const float* cosT = (const float*)d_in[5];
  const float* sinT = (const float*)d_in[6];
  float* out = (float*)d_out;

  const size_t NTOK = (size_t)B_ * T_;   // 4096
  const size_t SZ   = NTOK * D_;         // 4M elements
  unsigned short* xb   = (unsigned short*)d_ws;   // 8 MB (dead after gemm_qkv)
  unsigned short* Wp   = xb + SZ;                 // 8 MB (wq|wk|wv|wo)
  unsigned short* QKVh = Wp + 4 * 1048576;        // 24 MB (Q|K|V)
  unsigned short* Ab   = QKVh + 3 * SZ;           // 8 MB
  unsigned short* VTb  = xb;                      // reuse xb for V^T

  cast_all<<<4096, 256, 0, stream>>>(x, wq, wk, wv, wo, xb, Wp);
  gemm_qkv<<<dim3(24, 32), 256, 0, stream>>>(xb, Wp, QKVh, cosT, sinT);
  vtrans<<<dim3(32, 16, 2), 256, 0, stream>>>(QKVh + 2 * SZ, VTb);
  attn_kernel<<<512, 512, 0, stream>>>(QKVh, QKVh + SZ, VTb, Ab);
  gemm_out<<<dim3(8, 64), 256, 0, stream>>>(Ab, Wp + 3 * 1048576, out);
}